// Round 1
// baseline (15027.020 us; speedup 1.0000x reference)
//
#include <hip/hip_runtime.h>

// ---------------------------------------------------------------------------
// RNNDecoder: embedding -> 2x LSTM (seq recurrence) -> MHA over encoder ->
// word scatter (mis) -> fc1(tanh) -> fc2 -> log_softmax.
// B=32 L=513 S=1024 H=512 HEADS=4 dh=128 NCLS=128.
// Strategy: bf16 MFMA (16x16x32) for all GEMMs, f32 accumulate; persistent
// 64-block recurrence kernel with LDS-resident w_hh slice and a global
// atomic barrier per timestep (device-scope fences for cross-XCD coherence).
// ---------------------------------------------------------------------------

typedef __attribute__((ext_vector_type(8))) short bf16x8;
typedef __attribute__((ext_vector_type(4))) float f32x4;

__device__ __forceinline__ unsigned short f2bf(float f) {
  union { float f; unsigned int u; } v; v.f = f;
  unsigned int r = (v.u + 0x7fffu + ((v.u >> 16) & 1u)) >> 16;
  return (unsigned short)r;
}
__device__ __forceinline__ float bf2f(unsigned short h) {
  union { unsigned int u; float f; } v; v.u = ((unsigned int)h) << 16;
  return v.f;
}

typedef const __attribute__((address_space(1))) void* gp1_t;
typedef __attribute__((address_space(3))) void* lp3_t;
__device__ __forceinline__ void glds16(const void* g, void* s) {
  __builtin_amdgcn_global_load_lds((gp1_t)g, (lp3_t)s, 16, 0, 0);
}

// ---------------------------------------------------------------------------
// Generic bf16 GEMM:  C[m][n] = act( alpha * sum_k A[m][k]*W[n][k] + bias[n] )
// A: M x K (row major, lda), W: N x K (row major, ldw)  ("B^T" layout).
// Batched over z (z = zb*heads + zh) via element offsets.
// 128x128 tile, BK=32, 4 waves, each wave 64x64 via 4x4 MFMA 16x16x32.
// ---------------------------------------------------------------------------
struct Gemm {
  const unsigned short* A; const unsigned short* W; const float* bias;
  float* C1; unsigned short* C2;
  long lda, ldw, ldc1, ldc2;
  long zA, zAh, zW, zWh, zC1, zC1h, zC2, zC2h;
  long M, Mclamp;
  int N, K, heads, act;
  float alpha;
};

__global__ __launch_bounds__(256, 2) void gemm_bt(Gemm g) {
  __shared__ unsigned short aSh[128 * 32];
  __shared__ unsigned short bSh[128 * 32];
  const int tid = threadIdx.x;
  const int wave = tid >> 6, lane = tid & 63;
  const int zb = blockIdx.z / g.heads, zh = blockIdx.z % g.heads;
  const unsigned short* A = g.A + (long)zb * g.zA + (long)zh * g.zAh;
  const unsigned short* W = g.W + (long)zb * g.zW + (long)zh * g.zWh;
  const long mBlk = (long)blockIdx.y * 128;
  const long nBlk = (long)blockIdx.x * 128;
  const int sRow = wave * 16 + (lane >> 2);
  const int sCol = (lane & 3) * 8;
  long ar0 = mBlk + sRow;      if (ar0 > g.Mclamp) ar0 = g.Mclamp;
  long ar1 = mBlk + 64 + sRow; if (ar1 > g.Mclamp) ar1 = g.Mclamp;
  const unsigned short* gA0 = A + ar0 * g.lda + sCol;
  const unsigned short* gA1 = A + ar1 * g.lda + sCol;
  const unsigned short* gW0 = W + (nBlk + sRow) * g.ldw + sCol;
  const unsigned short* gW1 = W + (nBlk + 64 + sRow) * g.ldw + sCol;
  unsigned short* sA0 = aSh + wave * 512;
  unsigned short* sA1 = aSh + 2048 + wave * 512;
  unsigned short* sB0 = bSh + wave * 512;
  unsigned short* sB1 = bSh + 2048 + wave * 512;
  f32x4 acc[4][4] = {};
  const int wm = wave & 1, wn = wave >> 1;
  const int fm = lane & 15, fq = lane >> 4;
  for (int k0 = 0; k0 < g.K; k0 += 32) {
    glds16(gA0 + k0, sA0);
    glds16(gA1 + k0, sA1);
    glds16(gW0 + k0, sB0);
    glds16(gW1 + k0, sB1);
    __syncthreads();
    bf16x8 af[4], bfr[4];
#pragma unroll
    for (int i = 0; i < 4; ++i)
      af[i] = *(const bf16x8*)(aSh + (wm * 64 + i * 16 + fm) * 32 + fq * 8);
#pragma unroll
    for (int j = 0; j < 4; ++j)
      bfr[j] = *(const bf16x8*)(bSh + (wn * 64 + j * 16 + fm) * 32 + fq * 8);
#pragma unroll
    for (int i = 0; i < 4; ++i)
#pragma unroll
      for (int j = 0; j < 4; ++j)
        acc[i][j] = __builtin_amdgcn_mfma_f32_16x16x32_bf16(af[i], bfr[j], acc[i][j], 0, 0, 0);
    __syncthreads();
  }
  float* C1 = g.C1 ? g.C1 + (long)zb * g.zC1 + (long)zh * g.zC1h : nullptr;
  unsigned short* C2 = g.C2 ? g.C2 + (long)zb * g.zC2 + (long)zh * g.zC2h : nullptr;
#pragma unroll
  for (int j = 0; j < 4; ++j) {
    long n = nBlk + wn * 64 + j * 16 + fm;
    float bias = g.bias ? g.bias[n] : 0.f;
#pragma unroll
    for (int i = 0; i < 4; ++i) {
      long mBase = mBlk + wm * 64 + i * 16 + fq * 4;
#pragma unroll
      for (int r = 0; r < 4; ++r) {
        long m = mBase + r;
        if (m < g.M) {
          float v = acc[i][j][r] * g.alpha + bias;
          if (g.act) v = tanhf(v);
          if (C1) C1[m * g.ldc1 + n] = v;
          if (C2) C2[m * g.ldc2 + n] = f2bf(v);
        }
      }
    }
  }
}

// ---------------------------------------------------------------------------
// Persistent LSTM recurrence. 64 blocks; block bx owns h-indices
// [bx*8, bx*8+8) i.e. 32 w_hh rows (i,f,g,o interleaved by chunks of 8) in
// LDS. Per step: gates = xp[:,t,:] + h_{t-1} @ w_hh^T via MFMA; combine;
// write bf16 h; global barrier.
// ---------------------------------------------------------------------------
__global__ __launch_bounds__(256, 1) void lstm_rec(
    const float* __restrict__ xp,        // (b*513+t)*2048
    const unsigned short* __restrict__ whh,  // 2048 x 512 bf16
    unsigned short* hbuf,                // rows (b*513+t)*hstride, h at cols [0,512)
    long hstride, unsigned int* bar) {
  __shared__ unsigned short wSh[32 * 520];  // pad 512->520 (16B-aligned, 2-way banks)
  __shared__ float gSh[32 * 33];
  const int tid = threadIdx.x, lane = tid & 63, wave = tid >> 6;
  const int j0 = blockIdx.x * 8;
  {
    const int row = tid >> 3;            // 0..31  (gate = row>>3, jl = row&7)
    const int cb = (tid & 7) * 64;
    const unsigned short* src = whh + ((long)((row >> 3) * 512 + j0 + (row & 7))) * 512 + cb;
    unsigned short* dst = wSh + row * 520 + cb;
#pragma unroll
    for (int c = 0; c < 64; c += 8) *(bf16x8*)(dst + c) = *(const bf16x8*)(src + c);
  }
  __syncthreads();
  const int wm = wave & 1, wn = wave >> 1;
  const int fm = lane & 15, fq = lane >> 4;
  const unsigned short* wrow = wSh + (wn * 16 + fm) * 520 + fq * 8;
  const long ab = wm * 16 + fm;          // batch row for A fragment
  const int cbat = tid >> 3;             // combine: batch
  const int jl = tid & 7;                // combine: j within chunk
  const float* xpBase = xp + (long)cbat * 513 * 2048 + j0 + jl;
  unsigned short* hOut = hbuf + (long)cbat * 513 * hstride + j0 + jl;
  float cSt = 0.f;
  for (int t = 0; t < 513; ++t) {
    f32x4 acc = {0.f, 0.f, 0.f, 0.f};
    if (t > 0) {
      const unsigned short* hrow = hbuf + (ab * 513 + (t - 1)) * hstride + fq * 8;
#pragma unroll
      for (int kk = 0; kk < 16; ++kk) {
        bf16x8 a = *(const bf16x8*)(hrow + kk * 32);
        bf16x8 b = *(const bf16x8*)(wrow + kk * 32);
        acc = __builtin_amdgcn_mfma_f32_16x16x32_bf16(a, b, acc, 0, 0, 0);
      }
    }
#pragma unroll
    for (int r = 0; r < 4; ++r)
      gSh[(wn * 16 + fm) * 33 + wm * 16 + fq * 4 + r] = acc[r];
    __syncthreads();
    {
      const float* xpp = xpBase + (long)t * 2048;
      float gi = gSh[(jl) * 33 + cbat] + xpp[0];
      float gf = gSh[(8 + jl) * 33 + cbat] + xpp[512];
      float gg = gSh[(16 + jl) * 33 + cbat] + xpp[1024];
      float go = gSh[(24 + jl) * 33 + cbat] + xpp[1536];
      float ig = 1.f / (1.f + __expf(-gi));
      float fg = 1.f / (1.f + __expf(-gf));
      float og = 1.f / (1.f + __expf(-go));
      cSt = fg * cSt + ig * tanhf(gg);
      hOut[(long)t * hstride] = f2bf(og * tanhf(cSt));
    }
    __threadfence();            // release my h stores to agent scope
    __syncthreads();
    if (tid == 0) {
      __hip_atomic_fetch_add(bar, 1u, __ATOMIC_RELAXED, __HIP_MEMORY_SCOPE_AGENT);
      const unsigned int tgt = 64u * (unsigned)(t + 1);
      while (__hip_atomic_load(bar, __ATOMIC_RELAXED, __HIP_MEMORY_SCOPE_AGENT) < tgt)
        __builtin_amdgcn_s_sleep(1);
    }
    __syncthreads();
    __threadfence();            // acquire: invalidate stale L1/L2 before next reads
  }
}

// --------------------------- small kernels ---------------------------------

struct CastJob { const float* src; unsigned short* dst; long n; };
struct CastJobs { CastJob j[11]; };
__global__ void cast_multi(CastJobs jb) {
  const CastJob j = jb.j[blockIdx.z];
  long n4 = j.n >> 2;
  for (long i = blockIdx.x * (long)blockDim.x + threadIdx.x; i < n4;
       i += (long)gridDim.x * blockDim.x) {
    float4 f = ((const float4*)j.src)[i];
    ushort4 o;
    o.x = f2bf(f.x); o.y = f2bf(f.y); o.z = f2bf(f.z); o.w = f2bf(f.w);
    ((ushort4*)j.dst)[i] = o;
  }
}

__global__ void bias_sum(const float* a0, const float* b0, float* o0,
                         const float* a1, const float* b1, float* o1) {
  int i = blockIdx.x * 256 + threadIdx.x;
  if (i < 2048) { o0[i] = a0[i] + b0[i]; o1[i] = a1[i] + b1[i]; }
}

__global__ __launch_bounds__(256) void embed_gather(const int* __restrict__ tg,
                                                    const unsigned short* __restrict__ emb,
                                                    unsigned short* __restrict__ out) {
  long row = blockIdx.x;                // 0..16415 = b*513+t
  int id = tg[row];
  const unsigned short* s = emb + (long)id * 512;
  unsigned short* d = out + row * 512;
  int c = threadIdx.x * 2;
  *(ushort2*)(d + c) = *(const ushort2*)(s + c);
}

__global__ void word_map(const int* __restrict__ tg, int* __restrict__ map) {
  int b = threadIdx.x;
  if (b >= 32) return;
  int word_id = 0, start = 0;
  for (int i = 0; i < 512; ++i) {
    int id = tg[b * 513 + i + 1];
    bool bd = (id == 1) || (id == 0);   // SPACE or PAD
    if (bd) {
      map[b * 512 + i] = -1;
      word_id++; start = i + 1;
    } else {
      int pos = i - start; if (pos > 6) pos = 6;
      map[b * 512 + i] = (b * 64 + word_id) * 7 + pos;
    }
  }
}

__global__ __launch_bounds__(256) void vtrans(const unsigned short* __restrict__ v,
                                              unsigned short* __restrict__ vt) {
  __shared__ unsigned short tile[64][33];
  const int bh = blockIdx.z, b = bh >> 2, h = bh & 3;
  const int s0 = blockIdx.x * 64, d0 = blockIdx.y * 32;
  const int tid = threadIdx.x;
  {
    const int dd = tid & 31, sb = tid >> 5;
#pragma unroll
    for (int k = 0; k < 8; ++k) {
      int s = sb + k * 8;
      tile[s][dd] = v[((long)b * 1024 + s0 + s) * 512 + h * 128 + d0 + dd];
    }
  }
  __syncthreads();
  {
    const int ss = tid & 63, db = tid >> 6;
#pragma unroll
    for (int k = 0; k < 8; ++k) {
      int d = db + k * 4;
      vt[((long)bh * 128 + d0 + d) * 1024 + s0 + ss] = tile[ss][d0 ? (d) : (d)];
    }
  }
}

__global__ __launch_bounds__(256) void softmax_row(unsigned short* __restrict__ sc,
                                                   float* __restrict__ attnOut) {
  const long row = blockIdx.x;          // (b*4+h)*513 + t
  unsigned short* sr = sc + row * 1024;
  const int tid = threadIdx.x, lane = tid & 63, wave = tid >> 6;
  __shared__ float red[8];
  ushort4 raw = *(const ushort4*)(sr + tid * 4);
  float v0 = bf2f(raw.x), v1 = bf2f(raw.y), v2 = bf2f(raw.z), v3 = bf2f(raw.w);
  float m = fmaxf(fmaxf(v0, v1), fmaxf(v2, v3));
  for (int o = 32; o; o >>= 1) m = fmaxf(m, __shfl_down(m, o));
  if (lane == 0) red[wave] = m;
  __syncthreads();
  m = fmaxf(fmaxf(red[0], red[1]), fmaxf(red[2], red[3]));
  float e0 = __expf(v0 - m), e1 = __expf(v1 - m), e2 = __expf(v2 - m), e3 = __expf(v3 - m);
  float s = e0 + e1 + e2 + e3;
  for (int o = 32; o; o >>= 1) s += __shfl_down(s, o);
  if (lane == 0) red[4 + wave] = s;
  __syncthreads();
  float inv = 1.f / (red[4] + red[5] + red[6] + red[7]);
  float a0 = e0 * inv, a1 = e1 * inv, a2 = e2 * inv, a3 = e3 * inv;
  float4 fo; fo.x = a0; fo.y = a1; fo.z = a2; fo.w = a3;
  *(float4*)(attnOut + row * 1024 + tid * 4) = fo;
  ushort4 ob; ob.x = f2bf(a0); ob.y = f2bf(a1); ob.z = f2bf(a2); ob.w = f2bf(a3);
  *(ushort4*)(sr + tid * 4) = ob;       // in-place bf16 attn for ctx GEMM
}

__global__ __launch_bounds__(128) void mis_scatter(const int* __restrict__ map,
                                                   const int* __restrict__ tg,
                                                   const float* __restrict__ emb_w,
                                                   const float* __restrict__ ctx,
                                                   float* __restrict__ mis) {
  int bi = blockIdx.x;                  // b*512 + i
  int g = map[bi];
  if (g < 0) return;
  int b = bi >> 9, i = bi & 511;
  float* dst = mis + (long)g * 1024;
  int id = tg[b * 513 + i + 1];
  const float* es = emb_w + (long)id * 512;
  const float* cs = ctx + ((long)b * 513 + i) * 512;
  for (int c = threadIdx.x; c < 512; c += 128) {
    dst[c] = es[c];
    dst[512 + c] = cs[c];
  }
}

__global__ __launch_bounds__(256) void logsoftmax_rows(const float* __restrict__ logits,
                                                       float* __restrict__ out) {
  int row = blockIdx.x * 4 + (threadIdx.x >> 6);
  if (row >= 16416) return;
  int lane = threadIdx.x & 63;
  const float* lr = logits + (long)row * 128;
  float a = lr[lane], b = lr[lane + 64];
  float m = fmaxf(a, b);
  for (int o = 32; o; o >>= 1) m = fmaxf(m, __shfl_down(m, o));
  m = __shfl(m, 0);
  float s = __expf(a - m) + __expf(b - m);
  for (int o = 32; o; o >>= 1) s += __shfl_down(s, o);
  s = __shfl(s, 0);
  float ls = m + __logf(s);
  out[(long)row * 128 + lane] = a - ls;
  out[(long)row * 128 + lane + 64] = b - ls;
}

// ---------------------------------------------------------------------------

extern "C" void kernel_launch(void* const* d_in, const int* in_sizes, int n_in,
                              void* d_out, int out_size, void* d_ws, size_t ws_size,
                              hipStream_t stream) {
  (void)in_sizes; (void)n_in; (void)out_size; (void)ws_size;
  const int*   targets = (const int*)d_in[0];
  const float* enc   = (const float*)d_in[1];
  const float* emb_w = (const float*)d_in[2];
  const float* w_ih0 = (const float*)d_in[3];
  const float* w_hh0 = (const float*)d_in[4];
  const float* b_ih0 = (const float*)d_in[5];
  const float* b_hh0 = (const float*)d_in[6];
  const float* w_ih1 = (const float*)d_in[7];
  const float* w_hh1 = (const float*)d_in[8];
  const float* b_ih1 = (const float*)d_in[9];
  const float* b_hh1 = (const float*)d_in[10];
  const float* q_w = (const float*)d_in[11]; const float* q_b = (const float*)d_in[12];
  const float* k_w = (const float*)d_in[13]; const float* k_b = (const float*)d_in[14];
  const float* v_w = (const float*)d_in[15]; const float* v_b = (const float*)d_in[16];
  const float* fc1_w = (const float*)d_in[17]; const float* fc1_b = (const float*)d_in[18];
  const float* fc2_w = (const float*)d_in[19]; const float* fc2_b = (const float*)d_in[20];

  float* out_logp = (float*)d_out;
  float* out_attn = out_logp + 2101248;          // (32,4,513,1024)
  float* out_mis  = out_logp + 69341184;         // (2048,7,1024)

  // workspace arena (~425 MB)
  char* ws = (char*)d_ws;
  size_t off = 0;
  auto take = [&](size_t bytes) -> char* {
    char* p = ws + off; off += (bytes + 255) & ~(size_t)255; return p;
  };
  unsigned int* bar   = (unsigned int*)take(1024);
  int* map            = (int*)take(65536);
  float* bias0        = (float*)take(8192);
  float* bias1        = (float*)take(8192);
  unsigned short* wih0b = (unsigned short*)take(2097152);
  unsigned short* whh0b = (unsigned short*)take(2097152);
  unsigned short* wih1b = (unsigned short*)take(2097152);
  unsigned short* whh1b = (unsigned short*)take(2097152);
  unsigned short* qwb   = (unsigned short*)take(524288);
  unsigned short* kwb   = (unsigned short*)take(524288);
  unsigned short* vwb   = (unsigned short*)take(524288);
  unsigned short* fc1wb = (unsigned short*)take(1048576);
  unsigned short* fc2wb = (unsigned short*)take(131072);
  unsigned short* embb  = (unsigned short*)take(131072);
  unsigned short* emb_bf = (unsigned short*)take(16908288);  // embedded bf16 (16512x512)
  unsigned short* enc_bf = (unsigned short*)take(33554432);  // (32768x512)
  float* xp             = (float*)take(135266304);           // (16512x2048) f32; aliased by scores
  unsigned short* scores = (unsigned short*)xp;              // (128,513,1024) bf16 alias
  unsigned short* h0_bf = (unsigned short*)take(16908288);   // (16512x512)
  unsigned short* cat_bf = (unsigned short*)take(33816576);  // (16512x1024): [h1 | ctx]
  unsigned short* q_bf  = (unsigned short*)take(16908288);
  unsigned short* k_bf  = (unsigned short*)take(33554432);
  unsigned short* v_bf  = (unsigned short*)take(33554432);
  unsigned short* v_t   = (unsigned short*)take(33554432);   // (128,128,1024)
  float* ctx            = (float*)take(33816576);            // (16512x512)
  unsigned short* h1_bf = (unsigned short*)take(16908288);
  float* logits         = (float*)take(8454144);             // (16512x128)

  hipMemsetAsync(bar, 0, 1024, stream);
  hipMemsetAsync(out_mis, 0, (size_t)14680064 * 4, stream);

  // weight casts
  CastJobs cj;
  cj.j[0]  = {w_ih0, wih0b, 1048576};
  cj.j[1]  = {w_hh0, whh0b, 1048576};
  cj.j[2]  = {w_ih1, wih1b, 1048576};
  cj.j[3]  = {w_hh1, whh1b, 1048576};
  cj.j[4]  = {q_w,   qwb,   262144};
  cj.j[5]  = {k_w,   kwb,   262144};
  cj.j[6]  = {v_w,   vwb,   262144};
  cj.j[7]  = {fc1_w, fc1wb, 524288};
  cj.j[8]  = {fc2_w, fc2wb, 65536};
  cj.j[9]  = {emb_w, embb,  65536};
  cj.j[10] = {enc,   enc_bf, 16777216};
  cast_multi<<<dim3(256, 1, 11), 256, 0, stream>>>(cj);
  bias_sum<<<8, 256, 0, stream>>>(b_ih0, b_hh0, bias0, b_ih1, b_hh1, bias1);
  word_map<<<1, 64, 0, stream>>>(targets, map);
  embed_gather<<<16416, 256, 0, stream>>>(targets, embb, emb_bf);

  auto launch_gemm = [&](const unsigned short* A, long lda, long zA, long zAh,
                         const unsigned short* W, long ldw, long zW, long zWh,
                         const float* bias, float* C1, long ldc1, long zC1, long zC1h,
                         unsigned short* C2, long ldc2, long zC2, long zC2h,
                         long M, long Mclamp, int N, int K, int heads, int Z,
                         float alpha, int act) {
    Gemm g;
    g.A = A; g.W = W; g.bias = bias; g.C1 = C1; g.C2 = C2;
    g.lda = lda; g.ldw = ldw; g.ldc1 = ldc1; g.ldc2 = ldc2;
    g.zA = zA; g.zAh = zAh; g.zW = zW; g.zWh = zWh;
    g.zC1 = zC1; g.zC1h = zC1h; g.zC2 = zC2; g.zC2h = zC2h;
    g.M = M; g.Mclamp = Mclamp; g.N = N; g.K = K; g.heads = heads;
    g.act = act; g.alpha = alpha;
    dim3 grid((unsigned)(N / 128), (unsigned)((M + 127) / 128), (unsigned)Z);
    gemm_bt<<<grid, 256, 0, stream>>>(g);
  };

  // xp0 = embedded @ w_ih0^T + (b_ih0 + b_hh0)
  launch_gemm(emb_bf, 512, 0, 0, wih0b, 512, 0, 0, bias0,
              xp, 2048, 0, 0, nullptr, 0, 0, 0,
              16512, 16511, 2048, 512, 1, 1, 1.f, 0);
  // LSTM layer 0
  lstm_rec<<<64, 256, 0, stream>>>(xp, whh0b, h0_bf, 512, bar);
  // xp1 = h0 @ w_ih1^T + (b_ih1 + b_hh1)
  launch_gemm(h0_bf, 512, 0, 0, wih1b, 512, 0, 0, bias1,
              xp, 2048, 0, 0, nullptr, 0, 0, 0,
              16512, 16511, 2048, 512, 1, 1, 1.f, 0);
  // LSTM layer 1 -> left half of cat_bf
  lstm_rec<<<64, 256, 0, stream>>>(xp, whh1b, cat_bf, 1024, bar + 32);

  // q / k / v projections (bf16 outputs)
  launch_gemm(cat_bf, 1024, 0, 0, qwb, 512, 0, 0, q_b,
              nullptr, 0, 0, 0, q_bf, 512, 0, 0,
              16512, 16511, 512, 512, 1, 1, 1.f, 0);
  launch_gemm(enc_bf, 512, 0, 0, kwb, 512, 0, 0, k_b,
              nullptr, 0, 0, 0, k_bf, 512, 0, 0,
              32768, 32767, 512, 512, 1, 1, 1.f, 0);
  launch_gemm(enc_bf, 512, 0, 0, vwb, 512, 0, 0, v_b,
              nullptr, 0, 0, 0, v_bf, 512, 0, 0,
              32768, 32767, 512, 512, 1, 1, 1.f, 0);
  vtrans<<<dim3(16, 4, 128), 256, 0, stream>>>(v_bf, v_t);

  // scores[b,h,t,s] = (q . k) / sqrt(128)   (bf16, into xp alias)
  launch_gemm(q_bf, 512, 262656, 128, k_bf, 512, 524288, 128, nullptr,
              nullptr, 0, 0, 0, scores, 1024, 2101248, 525312,
              513, 512, 1024, 128, 4, 128, 0.08838834764831845f, 0);
  // softmax rows -> attn f32 out + bf16 in place
  softmax_row<<<65664, 256, 0, stream>>>(scores, out_attn);
  // ctx[b,t,h*128+d] = attn @ v   (f32 ctx + bf16 into cat_bf right half)
  launch_gemm(scores, 1024, 2101248, 525312, v_t, 1024, 524288, 131072, nullptr,
              ctx, 512, 262656, 128, cat_bf + 512, 1024, 525312, 128,
              513, 512, 128, 1024, 4, 128, 1.f, 0);
  // mis scatter (embedded f32 gather + ctx f32)
  mis_scatter<<<16384, 128, 0, stream>>>(map, targets, emb_w, ctx, out_mis);

  // fc1: tanh(cat @ fc1_w^T + b) -> bf16
  launch_gemm(cat_bf, 1024, 0, 0, fc1wb, 1024, 0, 0, fc1_b,
              nullptr, 0, 0, 0, h1_bf, 512, 0, 0,
              16512, 16511, 512, 1024, 1, 1, 1.f, 1);
  // fc2: logits f32
  launch_gemm(h1_bf, 512, 0, 0, fc2wb, 512, 0, 0, fc2_b,
              logits, 128, 0, 0, nullptr, 0, 0, 0,
              16512, 16511, 128, 512, 1, 1, 1.f, 0);
  // log_softmax -> d_out
  logsoftmax_rows<<<4104, 256, 0, stream>>>(logits, out_logp);
}

// Round 2
// 4106.294 us; speedup vs baseline: 3.6595x; 3.6595x over previous
//
#include <hip/hip_runtime.h>

// ---------------------------------------------------------------------------
// RNNDecoder: embedding -> 2x LSTM (fused persistent recurrence) -> MHA over
// encoder -> word scatter (mis) -> fc1(tanh) -> fc2 -> log_softmax.
// B=32 L=513 S=1024 H=512 HEADS=4 dh=128 NCLS=128.
// Round 2: fence-free recurrence. h exchange via relaxed agent-scope (sc1)
// atomic load/store so only shared data pays cross-XCD cost; L2 stays warm
// for xp. Both layers fused & pipelined: 513 barrier rounds instead of 1026.
// ---------------------------------------------------------------------------

typedef __attribute__((ext_vector_type(8))) short bf16x8;
typedef __attribute__((ext_vector_type(4))) float f32x4;

union U128 { unsigned long long q[2]; bf16x8 v; };

__device__ __forceinline__ unsigned short f2bf(float f) {
  union { float f; unsigned int u; } v; v.f = f;
  unsigned int r = (v.u + 0x7fffu + ((v.u >> 16) & 1u)) >> 16;
  return (unsigned short)r;
}
__device__ __forceinline__ float bf2f(unsigned short h) {
  union { unsigned int u; float f; } v; v.u = ((unsigned int)h) << 16;
  return v.f;
}

// device-scope (cross-XCD coherent, bypasses stale L1/L2) 8B load/store
__device__ __forceinline__ unsigned long long ld_dev(const unsigned short* p) {
  return __hip_atomic_load((const unsigned long long*)p, __ATOMIC_RELAXED,
                           __HIP_MEMORY_SCOPE_AGENT);
}
__device__ __forceinline__ void st_dev(unsigned short* p, unsigned long long x) {
  __hip_atomic_store((unsigned long long*)p, x, __ATOMIC_RELAXED,
                     __HIP_MEMORY_SCOPE_AGENT);
}

typedef const __attribute__((address_space(1))) void* gp1_t;
typedef __attribute__((address_space(3))) void* lp3_t;
__device__ __forceinline__ void glds16(const void* g, void* s) {
  __builtin_amdgcn_global_load_lds((gp1_t)g, (lp3_t)s, 16, 0, 0);
}

// ---------------------------------------------------------------------------
// Generic bf16 GEMM:  C[m][n] = act( alpha * sum_k A[m][k]*W[n][k] + bias[n] )
// ---------------------------------------------------------------------------
struct Gemm {
  const unsigned short* A; const unsigned short* W; const float* bias;
  float* C1; unsigned short* C2;
  long lda, ldw, ldc1, ldc2;
  long zA, zAh, zW, zWh, zC1, zC1h, zC2, zC2h;
  long M, Mclamp;
  int N, K, heads, act;
  float alpha;
};

__global__ __launch_bounds__(256, 2) void gemm_bt(Gemm g) {
  __shared__ unsigned short aSh[128 * 32];
  __shared__ unsigned short bSh[128 * 32];
  const int tid = threadIdx.x;
  const int wave = tid >> 6, lane = tid & 63;
  const int zb = blockIdx.z / g.heads, zh = blockIdx.z % g.heads;
  const unsigned short* A = g.A + (long)zb * g.zA + (long)zh * g.zAh;
  const unsigned short* W = g.W + (long)zb * g.zW + (long)zh * g.zWh;
  const long mBlk = (long)blockIdx.y * 128;
  const long nBlk = (long)blockIdx.x * 128;
  const int sRow = wave * 16 + (lane >> 2);
  const int sCol = (lane & 3) * 8;
  long ar0 = mBlk + sRow;      if (ar0 > g.Mclamp) ar0 = g.Mclamp;
  long ar1 = mBlk + 64 + sRow; if (ar1 > g.Mclamp) ar1 = g.Mclamp;
  const unsigned short* gA0 = A + ar0 * g.lda + sCol;
  const unsigned short* gA1 = A + ar1 * g.lda + sCol;
  const unsigned short* gW0 = W + (nBlk + sRow) * g.ldw + sCol;
  const unsigned short* gW1 = W + (nBlk + 64 + sRow) * g.ldw + sCol;
  unsigned short* sA0 = aSh + wave * 512;
  unsigned short* sA1 = aSh + 2048 + wave * 512;
  unsigned short* sB0 = bSh + wave * 512;
  unsigned short* sB1 = bSh + 2048 + wave * 512;
  f32x4 acc[4][4] = {};
  const int wm = wave & 1, wn = wave >> 1;
  const int fm = lane & 15, fq = lane >> 4;
  for (int k0 = 0; k0 < g.K; k0 += 32) {
    glds16(gA0 + k0, sA0);
    glds16(gA1 + k0, sA1);
    glds16(gW0 + k0, sB0);
    glds16(gW1 + k0, sB1);
    __syncthreads();
    bf16x8 af[4], bfr[4];
#pragma unroll
    for (int i = 0; i < 4; ++i)
      af[i] = *(const bf16x8*)(aSh + (wm * 64 + i * 16 + fm) * 32 + fq * 8);
#pragma unroll
    for (int j = 0; j < 4; ++j)
      bfr[j] = *(const bf16x8*)(bSh + (wn * 64 + j * 16 + fm) * 32 + fq * 8);
#pragma unroll
    for (int i = 0; i < 4; ++i)
#pragma unroll
      for (int j = 0; j < 4; ++j)
        acc[i][j] = __builtin_amdgcn_mfma_f32_16x16x32_bf16(af[i], bfr[j], acc[i][j], 0, 0, 0);
    __syncthreads();
  }
  float* C1 = g.C1 ? g.C1 + (long)zb * g.zC1 + (long)zh * g.zC1h : nullptr;
  unsigned short* C2 = g.C2 ? g.C2 + (long)zb * g.zC2 + (long)zh * g.zC2h : nullptr;
#pragma unroll
  for (int j = 0; j < 4; ++j) {
    long n = nBlk + wn * 64 + j * 16 + fm;
    float bias = g.bias ? g.bias[n] : 0.f;
#pragma unroll
    for (int i = 0; i < 4; ++i) {
      long mBase = mBlk + wm * 64 + i * 16 + fq * 4;
#pragma unroll
      for (int r = 0; r < 4; ++r) {
        long m = mBase + r;
        if (m < g.M) {
          float v = acc[i][j][r] * g.alpha + bias;
          if (g.act) v = tanhf(v);
          if (C1) C1[m * g.ldc1 + n] = v;
          if (C2) C2[m * g.ldc2 + n] = f2bf(v);
        }
      }
    }
  }
}

// ---------------------------------------------------------------------------
// Fused 2-layer persistent LSTM. 192 blocks:
//   blocks 0..63   : layer 0, 8 h-cols each (w_hh0 slice 32x512 in LDS)
//   blocks 64..191 : layer 1, 4 h-cols each (w_ih1 + w_hh1 slices in LDS)
// Pipeline: round r: L0 computes h0[r]; L1 computes h1[r-1] (uses h0[r-1]).
// h exchange via sc1 (agent-scope) loads/stores only; no cache-wide fences.
// Barrier: 8 spread counters, monotonic target 192*(r+1).
// ---------------------------------------------------------------------------
__global__ __launch_bounds__(256, 1) void lstm_fused(
    const float* __restrict__ xp,             // (b*513+t)*2048, bias0 included
    const unsigned short* __restrict__ wih1,  // 2048x512
    const unsigned short* __restrict__ whh0,  // 2048x512
    const unsigned short* __restrict__ whh1,  // 2048x512
    const float* __restrict__ bias1,          // 2048 (b_ih1+b_hh1)
    unsigned short* __restrict__ h0,          // (b*513+t)*512
    unsigned short* __restrict__ h1,          // (b*513+t)*1024 (cat left half)
    unsigned int* bar) {
  __shared__ unsigned short wSh[2 * 16 * 520];          // 33280 B
  __shared__ float gS[1056];                            // 32 rows x 33
  __shared__ __align__(16) unsigned short hStage[256];
  const int tid = threadIdx.x, lane = tid & 63, wave = tid >> 6;
  const int bx = blockIdx.x;
  const int fm = lane & 15, fq = lane >> 4;

  if (bx < 64) {
    // ----------------------------- layer 0 --------------------------------
    const int j0 = bx * 8;
    {
      const int row = tid >> 3, cb = (tid & 7) * 64;   // row = g*8 + jl
      const unsigned short* wsrc =
          whh0 + ((long)((row >> 3) * 512 + j0 + (row & 7))) * 512 + cb;
      unsigned short* dst = wSh + row * 520 + cb;
#pragma unroll
      for (int c = 0; c < 64; c += 8) *(bf16x8*)(dst + c) = *(const bf16x8*)(wsrc + c);
    }
    __syncthreads();
    const int wm = wave & 1, wn = wave >> 1;
    const unsigned short* wrow = wSh + (wn * 16 + fm) * 520 + fq * 8;
    const long ab = wm * 16 + fm;
    const int cb2 = tid >> 3, jl = tid & 7;
    const float* xpp = xp + (long)cb2 * 513 * 2048 + j0 + jl;
    float cSt = 0.f;
    for (int r = 0; r < 514; ++r) {
      if (r < 513) {
        const int t = r;
        const float* xq = xpp + (long)t * 2048;
        float x0 = xq[0], x1 = xq[512], x2 = xq[1024], x3 = xq[1536];
        f32x4 acc = {0.f, 0.f, 0.f, 0.f};
        if (t > 0) {
          U128 afr[16];
          const unsigned short* hr = h0 + (ab * 513 + (t - 1)) * 512 + fq * 8;
#pragma unroll
          for (int kk = 0; kk < 16; ++kk) {
            afr[kk].q[0] = ld_dev(hr + kk * 32);
            afr[kk].q[1] = ld_dev(hr + kk * 32 + 4);
          }
#pragma unroll
          for (int kk = 0; kk < 16; ++kk)
            acc = __builtin_amdgcn_mfma_f32_16x16x32_bf16(
                afr[kk].v, *(const bf16x8*)(wrow + kk * 32), acc, 0, 0, 0);
        }
#pragma unroll
        for (int rr = 0; rr < 4; ++rr)
          gS[(wn * 16 + fm) * 33 + wm * 16 + fq * 4 + rr] = acc[rr];
        __syncthreads();
        {
          float gi = gS[jl * 33 + cb2] + x0;
          float gf = gS[(8 + jl) * 33 + cb2] + x1;
          float gg = gS[(16 + jl) * 33 + cb2] + x2;
          float go = gS[(24 + jl) * 33 + cb2] + x3;
          float ig = 1.f / (1.f + __expf(-gi));
          float fg = 1.f / (1.f + __expf(-gf));
          float og = 1.f / (1.f + __expf(-go));
          cSt = fg * cSt + ig * tanhf(gg);
          hStage[tid] = f2bf(og * tanhf(cSt));
        }
        __syncthreads();
        if (tid < 64) {
          const int b2 = tid >> 1, half = tid & 1;
          unsigned long long q = *(const unsigned long long*)(hStage + b2 * 8 + half * 4);
          st_dev(h0 + ((long)b2 * 513 + t) * 512 + j0 + half * 4, q);
        }
      }
      if (r < 513) {
        __syncthreads();   // drains vmcnt(0): h stores complete (release)
        if (tid == 0) {
          __hip_atomic_fetch_add(bar + (bx & 7) * 1024, 1u, __ATOMIC_RELAXED,
                                 __HIP_MEMORY_SCOPE_AGENT);
          const unsigned int tgt = 192u * (unsigned)(r + 1);
          for (;;) {
            unsigned int s = 0;
#pragma unroll
            for (int i = 0; i < 8; ++i)
              s += __hip_atomic_load(bar + i * 1024, __ATOMIC_RELAXED,
                                     __HIP_MEMORY_SCOPE_AGENT);
            if (s >= tgt) break;
            __builtin_amdgcn_s_sleep(1);
          }
        }
        __syncthreads();
      }
    }
  } else {
    // ----------------------------- layer 1 --------------------------------
    const int j0 = (bx - 64) * 4;
    {
      // 2 matrices x 16 rows (row = g*4 + jl) x 512
      const int mat = tid >> 7, row = (tid >> 3) & 15, cb = (tid & 7) * 64;
      const unsigned short* wsrc = (mat ? whh1 : wih1) +
          ((long)((row >> 2) * 512 + j0 + (row & 3))) * 512 + cb;
      unsigned short* dst = wSh + (mat * 16 + row) * 520 + cb;
#pragma unroll
      for (int c = 0; c < 64; c += 8) *(bf16x8*)(dst + c) = *(const bf16x8*)(wsrc + c);
    }
    __syncthreads();
    const int wm = wave & 1, ws = wave >> 1;   // ws: 0 = ih(h0[t]), 1 = hh(h1[t-1])
    const unsigned short* wrow = wSh + (ws * 16 + fm) * 520 + fq * 8;
    const long ab = wm * 16 + fm;
    const int cb2 = tid >> 2, jl = tid & 3;
    float bv0 = 0.f, bv1 = 0.f, bv2 = 0.f, bv3 = 0.f;
    if (tid < 128) {
      bv0 = bias1[j0 + jl];
      bv1 = bias1[512 + j0 + jl];
      bv2 = bias1[1024 + j0 + jl];
      bv3 = bias1[1536 + j0 + jl];
    }
    float cSt = 0.f;
    for (int r = 0; r < 514; ++r) {
      if (r >= 1) {
        const int t = r - 1;
        f32x4 acc = {0.f, 0.f, 0.f, 0.f};
        if (ws == 0 || t > 0) {
          U128 afr[16];
          const unsigned short* hr = (ws == 0)
              ? h0 + (ab * 513 + t) * 512 + fq * 8
              : h1 + (ab * 513 + (t - 1)) * 1024 + fq * 8;
#pragma unroll
          for (int kk = 0; kk < 16; ++kk) {
            afr[kk].q[0] = ld_dev(hr + kk * 32);
            afr[kk].q[1] = ld_dev(hr + kk * 32 + 4);
          }
#pragma unroll
          for (int kk = 0; kk < 16; ++kk)
            acc = __builtin_amdgcn_mfma_f32_16x16x32_bf16(
                afr[kk].v, *(const bf16x8*)(wrow + kk * 32), acc, 0, 0, 0);
        }
#pragma unroll
        for (int rr = 0; rr < 4; ++rr)
          gS[(ws * 16 + fm) * 33 + wm * 16 + fq * 4 + rr] = acc[rr];
        __syncthreads();
        if (tid < 128) {
          float gi = gS[jl * 33 + cb2]        + gS[(16 + jl) * 33 + cb2] + bv0;
          float gf = gS[(4 + jl) * 33 + cb2]  + gS[(20 + jl) * 33 + cb2] + bv1;
          float gg = gS[(8 + jl) * 33 + cb2]  + gS[(24 + jl) * 33 + cb2] + bv2;
          float go = gS[(12 + jl) * 33 + cb2] + gS[(28 + jl) * 33 + cb2] + bv3;
          float ig = 1.f / (1.f + __expf(-gi));
          float fg = 1.f / (1.f + __expf(-gf));
          float og = 1.f / (1.f + __expf(-go));
          cSt = fg * cSt + ig * tanhf(gg);
          hStage[tid] = f2bf(og * tanhf(cSt));
        }
        __syncthreads();
        if (tid < 32) {
          unsigned long long q = *(const unsigned long long*)(hStage + tid * 4);
          st_dev(h1 + ((long)tid * 513 + t) * 1024 + j0, q);
        }
      }
      if (r < 513) {
        __syncthreads();
        if (tid == 0) {
          __hip_atomic_fetch_add(bar + (bx & 7) * 1024, 1u, __ATOMIC_RELAXED,
                                 __HIP_MEMORY_SCOPE_AGENT);
          const unsigned int tgt = 192u * (unsigned)(r + 1);
          for (;;) {
            unsigned int s = 0;
#pragma unroll
            for (int i = 0; i < 8; ++i)
              s += __hip_atomic_load(bar + i * 1024, __ATOMIC_RELAXED,
                                     __HIP_MEMORY_SCOPE_AGENT);
            if (s >= tgt) break;
            __builtin_amdgcn_s_sleep(1);
          }
        }
        __syncthreads();
      }
    }
  }
}

// --------------------------- small kernels ---------------------------------

struct CastJob { const float* src; unsigned short* dst; long n; };
struct CastJobs { CastJob j[11]; };
__global__ void cast_multi(CastJobs jb) {
  const CastJob j = jb.j[blockIdx.z];
  long n4 = j.n >> 2;
  for (long i = blockIdx.x * (long)blockDim.x + threadIdx.x; i < n4;
       i += (long)gridDim.x * blockDim.x) {
    float4 f = ((const float4*)j.src)[i];
    ushort4 o;
    o.x = f2bf(f.x); o.y = f2bf(f.y); o.z = f2bf(f.z); o.w = f2bf(f.w);
    ((ushort4*)j.dst)[i] = o;
  }
}

__global__ void bias_sum(const float* a0, const float* b0, float* o0,
                         const float* a1, const float* b1, float* o1) {
  int i = blockIdx.x * 256 + threadIdx.x;
  if (i < 2048) { o0[i] = a0[i] + b0[i]; o1[i] = a1[i] + b1[i]; }
}

__global__ __launch_bounds__(256) void embed_gather(const int* __restrict__ tg,
                                                    const unsigned short* __restrict__ emb,
                                                    unsigned short* __restrict__ out) {
  long row = blockIdx.x;                // 0..16415 = b*513+t
  int id = tg[row];
  const unsigned short* s = emb + (long)id * 512;
  unsigned short* d = out + row * 512;
  int c = threadIdx.x * 2;
  *(ushort2*)(d + c) = *(const ushort2*)(s + c);
}

__global__ void word_map(const int* __restrict__ tg, int* __restrict__ map) {
  int b = threadIdx.x;
  if (b >= 32) return;
  int word_id = 0, start = 0;
  for (int i = 0; i < 512; ++i) {
    int id = tg[b * 513 + i + 1];
    bool bd = (id == 1) || (id == 0);   // SPACE or PAD
    if (bd) {
      map[b * 512 + i] = -1;
      word_id++; start = i + 1;
    } else {
      int pos = i - start; if (pos > 6) pos = 6;
      map[b * 512 + i] = (b * 64 + word_id) * 7 + pos;
    }
  }
}

__global__ __launch_bounds__(256) void vtrans(const unsigned short* __restrict__ v,
                                              unsigned short* __restrict__ vt) {
  __shared__ unsigned short tile[64][33];
  const int bh = blockIdx.z, b = bh >> 2, h = bh & 3;
  const int s0 = blockIdx.x * 64, d0 = blockIdx.y * 32;
  const int tid = threadIdx.x;
  {
    const int dd = tid & 31, sb = tid >> 5;
#pragma unroll
    for (int k = 0; k < 8; ++k) {
      int s = sb + k * 8;
      tile[s][dd] = v[((long)b * 1024 + s0 + s) * 512 + h * 128 + d0 + dd];
    }
  }
  __syncthreads();
  {
    const int ss = tid & 63, db = tid >> 6;
#pragma unroll
    for (int k = 0; k < 8; ++k) {
      int d = db + k * 4;
      vt[((long)bh * 128 + d0 + d) * 1024 + s0 + ss] = tile[ss][d];
    }
  }
}

__global__ __launch_bounds__(256) void softmax_row(unsigned short* __restrict__ sc,
                                                   float* __restrict__ attnOut) {
  const long row = blockIdx.x;          // (b*4+h)*513 + t
  unsigned short* sr = sc + row * 1024;
  const int tid = threadIdx.x, lane = tid & 63, wave = tid >> 6;
  __shared__ float red[8];
  ushort4 raw = *(const ushort4*)(sr + tid * 4);
  float v0 = bf2f(raw.x), v1 = bf2f(raw.y), v2 = bf2f(raw.z), v3 = bf2f(raw.w);
  float m = fmaxf(fmaxf(v0, v1), fmaxf(v2, v3));
  for (int o = 32; o; o >>= 1) m = fmaxf(m, __shfl_down(m, o));
  if (lane == 0) red[wave] = m;
  __syncthreads();
  m = fmaxf(fmaxf(red[0], red[1]), fmaxf(red[2], red[3]));
  float e0 = __expf(v0 - m), e1 = __expf(v1 - m), e2 = __expf(v2 - m), e3 = __expf(v3 - m);
  float s = e0 + e1 + e2 + e3;
  for (int o = 32; o; o >>= 1) s += __shfl_down(s, o);
  if (lane == 0) red[4 + wave] = s;
  __syncthreads();
  float inv = 1.f / (red[4] + red[5] + red[6] + red[7]);
  float a0 = e0 * inv, a1 = e1 * inv, a2 = e2 * inv, a3 = e3 * inv;
  float4 fo; fo.x = a0; fo.y = a1; fo.z = a2; fo.w = a3;
  *(float4*)(attnOut + row * 1024 + tid * 4) = fo;
  ushort4 ob; ob.x = f2bf(a0); ob.y = f2bf(a1); ob.z = f2bf(a2); ob.w = f2bf(a3);
  *(ushort4*)(sr + tid * 4) = ob;       // in-place bf16 attn for ctx GEMM
}

__global__ __launch_bounds__(128) void mis_scatter(const int* __restrict__ map,
                                                   const int* __restrict__ tg,
                                                   const float* __restrict__ emb_w,
                                                   const float* __restrict__ ctx,
                                                   float* __restrict__ mis) {
  int bi = blockIdx.x;                  // b*512 + i
  int g = map[bi];
  if (g < 0) return;
  int b = bi >> 9, i = bi & 511;
  float* dst = mis + (long)g * 1024;
  int id = tg[b * 513 + i + 1];
  const float* es = emb_w + (long)id * 512;
  const float* cs = ctx + ((long)b * 513 + i) * 512;
  for (int c = threadIdx.x; c < 512; c += 128) {
    dst[c] = es[c];
    dst[512 + c] = cs[c];
  }
}

__global__ __launch_bounds__(256) void logsoftmax_rows(const float* __restrict__ logits,
                                                       float* __restrict__ out) {
  int row = blockIdx.x * 4 + (threadIdx.x >> 6);
  if (row >= 16416) return;
  int lane = threadIdx.x & 63;
  const float* lr = logits + (long)row * 128;
  float a = lr[lane], b = lr[lane + 64];
  float m = fmaxf(a, b);
  for (int o = 32; o; o >>= 1) m = fmaxf(m, __shfl_down(m, o));
  m = __shfl(m, 0);
  float s = __expf(a - m) + __expf(b - m);
  for (int o = 32; o; o >>= 1) s += __shfl_down(s, o);
  s = __shfl(s, 0);
  float ls = m + __logf(s);
  out[(long)row * 128 + lane] = a - ls;
  out[(long)row * 128 + lane + 64] = b - ls;
}

// ---------------------------------------------------------------------------

extern "C" void kernel_launch(void* const* d_in, const int* in_sizes, int n_in,
                              void* d_out, int out_size, void* d_ws, size_t ws_size,
                              hipStream_t stream) {
  (void)in_sizes; (void)n_in; (void)out_size; (void)ws_size;
  const int*   targets = (const int*)d_in[0];
  const float* enc   = (const float*)d_in[1];
  const float* emb_w = (const float*)d_in[2];
  const float* w_ih0 = (const float*)d_in[3];
  const float* w_hh0 = (const float*)d_in[4];
  const float* b_ih0 = (const float*)d_in[5];
  const float* b_hh0 = (const float*)d_in[6];
  const float* w_ih1 = (const float*)d_in[7];
  const float* w_hh1 = (const float*)d_in[8];
  const float* b_ih1 = (const float*)d_in[9];
  const float* b_hh1 = (const float*)d_in[10];
  const float* q_w = (const float*)d_in[11]; const float* q_b = (const float*)d_in[12];
  const float* k_w = (const float*)d_in[13]; const float* k_b = (const float*)d_in[14];
  const float* v_w = (const float*)d_in[15]; const float* v_b = (const float*)d_in[16];
  const float* fc1_w = (const float*)d_in[17]; const float* fc1_b = (const float*)d_in[18];
  const float* fc2_w = (const float*)d_in[19]; const float* fc2_b = (const float*)d_in[20];

  float* out_logp = (float*)d_out;
  float* out_attn = out_logp + 2101248;          // (32,4,513,1024)
  float* out_mis  = out_logp + 69341184;         // (2048,7,1024)

  // workspace arena
  char* ws = (char*)d_ws;
  size_t off = 0;
  auto take = [&](size_t bytes) -> char* {
    char* p = ws + off; off += (bytes + 255) & ~(size_t)255; return p;
  };
  unsigned int* bar   = (unsigned int*)take(65536);   // 8 counters, 4KB apart
  int* map            = (int*)take(65536);
  float* bias0        = (float*)take(8192);
  float* bias1        = (float*)take(8192);
  unsigned short* wih0b = (unsigned short*)take(2097152);
  unsigned short* whh0b = (unsigned short*)take(2097152);
  unsigned short* wih1b = (unsigned short*)take(2097152);
  unsigned short* whh1b = (unsigned short*)take(2097152);
  unsigned short* qwb   = (unsigned short*)take(524288);
  unsigned short* kwb   = (unsigned short*)take(524288);
  unsigned short* vwb   = (unsigned short*)take(524288);
  unsigned short* fc1wb = (unsigned short*)take(1048576);
  unsigned short* fc2wb = (unsigned short*)take(131072);
  unsigned short* embb  = (unsigned short*)take(131072);
  unsigned short* emb_bf = (unsigned short*)take(16908288);  // (16512x512) bf16
  unsigned short* enc_bf = (unsigned short*)take(33554432);  // (32768x512)
  float* xp             = (float*)take(135266304);           // (16512x2048) f32; aliased by scores
  unsigned short* scores = (unsigned short*)xp;              // (128,513,1024) bf16 alias
  unsigned short* h0_bf = (unsigned short*)take(16908288);   // (16512x512)
  unsigned short* cat_bf = (unsigned short*)take(33816576);  // (16512x1024): [h1 | ctx]
  unsigned short* q_bf  = (unsigned short*)take(16908288);
  unsigned short* k_bf  = (unsigned short*)take(33554432);
  unsigned short* v_bf  = (unsigned short*)take(33554432);
  unsigned short* v_t   = (unsigned short*)take(33554432);   // (128,128,1024)
  float* ctx            = (float*)take(33816576);            // (16512x512)
  unsigned short* h1_bf = (unsigned short*)take(16908288);
  float* logits         = (float*)take(8454144);             // (16512x128)

  hipMemsetAsync(bar, 0, 32768, stream);
  hipMemsetAsync(out_mis, 0, (size_t)14680064 * 4, stream);

  // weight casts
  CastJobs cj;
  cj.j[0]  = {w_ih0, wih0b, 1048576};
  cj.j[1]  = {w_hh0, whh0b, 1048576};
  cj.j[2]  = {w_ih1, wih1b, 1048576};
  cj.j[3]  = {w_hh1, whh1b, 1048576};
  cj.j[4]  = {q_w,   qwb,   262144};
  cj.j[5]  = {k_w,   kwb,   262144};
  cj.j[6]  = {v_w,   vwb,   262144};
  cj.j[7]  = {fc1_w, fc1wb, 524288};
  cj.j[8]  = {fc2_w, fc2wb, 65536};
  cj.j[9]  = {emb_w, embb,  65536};
  cj.j[10] = {enc,   enc_bf, 16777216};
  cast_multi<<<dim3(256, 1, 11), 256, 0, stream>>>(cj);
  bias_sum<<<8, 256, 0, stream>>>(b_ih0, b_hh0, bias0, b_ih1, b_hh1, bias1);
  word_map<<<1, 64, 0, stream>>>(targets, map);
  embed_gather<<<16416, 256, 0, stream>>>(targets, embb, emb_bf);

  auto launch_gemm = [&](const unsigned short* A, long lda, long zA, long zAh,
                         const unsigned short* W, long ldw, long zW, long zWh,
                         const float* bias, float* C1, long ldc1, long zC1, long zC1h,
                         unsigned short* C2, long ldc2, long zC2, long zC2h,
                         long M, long Mclamp, int N, int K, int heads, int Z,
                         float alpha, int act) {
    Gemm g;
    g.A = A; g.W = W; g.bias = bias; g.C1 = C1; g.C2 = C2;
    g.lda = lda; g.ldw = ldw; g.ldc1 = ldc1; g.ldc2 = ldc2;
    g.zA = zA; g.zAh = zAh; g.zW = zW; g.zWh = zWh;
    g.zC1 = zC1; g.zC1h = zC1h; g.zC2 = zC2; g.zC2h = zC2h;
    g.M = M; g.Mclamp = Mclamp; g.N = N; g.K = K; g.heads = heads;
    g.act = act; g.alpha = alpha;
    dim3 grid((unsigned)(N / 128), (unsigned)((M + 127) / 128), (unsigned)Z);
    gemm_bt<<<grid, 256, 0, stream>>>(g);
  };

  // xp0 = embedded @ w_ih0^T + (b_ih0 + b_hh0)
  launch_gemm(emb_bf, 512, 0, 0, wih0b, 512, 0, 0, bias0,
              xp, 2048, 0, 0, nullptr, 0, 0, 0,
              16512, 16511, 2048, 512, 1, 1, 1.f, 0);
  // fused 2-layer recurrence: h0 -> h0_bf, h1 -> cat_bf left half
  lstm_fused<<<192, 256, 0, stream>>>(xp, wih1b, whh0b, whh1b, bias1,
                                      h0_bf, cat_bf, bar);

  // q / k / v projections (bf16 outputs)
  launch_gemm(cat_bf, 1024, 0, 0, qwb, 512, 0, 0, q_b,
              nullptr, 0, 0, 0, q_bf, 512, 0, 0,
              16512, 16511, 512, 512, 1, 1, 1.f, 0);
  launch_gemm(enc_bf, 512, 0, 0, kwb, 512, 0, 0, k_b,
              nullptr, 0, 0, 0, k_bf, 512, 0, 0,
              32768, 32767, 512, 512, 1, 1, 1.f, 0);
  launch_gemm(enc_bf, 512, 0, 0, vwb, 512, 0, 0, v_b,
              nullptr, 0, 0, 0, v_bf, 512, 0, 0,
              32768, 32767, 512, 512, 1, 1, 1.f, 0);
  vtrans<<<dim3(16, 4, 128), 256, 0, stream>>>(v_bf, v_t);

  // scores[b,h,t,s] = (q . k) / sqrt(128)   (bf16, into xp alias)
  launch_gemm(q_bf, 512, 262656, 128, k_bf, 512, 524288, 128, nullptr,
              nullptr, 0, 0, 0, scores, 1024, 2101248, 525312,
              513, 512, 1024, 128, 4, 128, 0.08838834764831845f, 0);
  // softmax rows -> attn f32 out + bf16 in place
  softmax_row<<<65664, 256, 0, stream>>>(scores, out_attn);
  // ctx[b,t,h*128+d] = attn @ v   (f32 ctx + bf16 into cat_bf right half)
  launch_gemm(scores, 1024, 2101248, 525312, v_t, 1024, 524288, 131072, nullptr,
              ctx, 512, 262656, 128, cat_bf + 512, 1024, 525312, 128,
              513, 512, 128, 1024, 4, 128, 1.f, 0);
  // mis scatter (embedded f32 gather + ctx f32)
  mis_scatter<<<16384, 128, 0, stream>>>(map, targets, emb_w, ctx, out_mis);

  // fc1: tanh(cat @ fc1_w^T + b) -> bf16
  launch_gemm(cat_bf, 1024, 0, 0, fc1wb, 1024, 0, 0, fc1_b,
              nullptr, 0, 0, 0, h1_bf, 512, 0, 0,
              16512, 16511, 512, 1024, 1, 1, 1.f, 1);
  // fc2: logits f32
  launch_gemm(h1_bf, 512, 0, 0, fc2wb, 512, 0, 0, fc2_b,
              logits, 128, 0, 0, nullptr, 0, 0, 0,
              16512, 16511, 128, 512, 1, 1, 1.f, 0);
  // log_softmax -> d_out
  logsoftmax_rows<<<4104, 256, 0, stream>>>(logits, out_logp);
}